// Round 6
// baseline (1244.487 us; speedup 1.0000x reference)
//
#include <hip/hip_runtime.h>
#include <math.h>

#define NB   8
#define LLEN 2048
#define HDIM 1024
#define LNEPS 1e-5f

#define BM 256
#define BN 256
#define BK 64
#define NT_K (HDIM / BK)   // 16 K-tiles
#define NTHR 512
#define SLOT (BM * BK)     // 16384 shorts = 32 KiB per operand slot

typedef __attribute__((ext_vector_type(8))) short short8;
typedef __attribute__((ext_vector_type(4))) unsigned short ushort4v;
typedef __attribute__((ext_vector_type(4))) float f32x4;

typedef __attribute__((address_space(3))) void lds_void;
typedef const __attribute__((address_space(1))) void glob_void;

__device__ __forceinline__ unsigned short f2bf(float f) {
    union { float f; unsigned u; } v; v.f = f;
    unsigned r = v.u + 0x7FFFu + ((v.u >> 16) & 1u);
    return (unsigned short)(r >> 16);
}
__device__ __forceinline__ float bf2f(unsigned short h) {
    union { unsigned u; float f; } v; v.u = ((unsigned)h) << 16;
    return v.f;
}

// One fill step: stages 64 rows (s-th quarter) of a 256x64 bf16 tile into an
// LDS slot with XOR-swizzled layout byte(r,cb) = r*128 + (cb ^ ((r&7)<<4)).
// global_load_lds writes linearly, so the swizzle is pre-applied to the
// per-lane GLOBAL source column (rule 21: both-sides-or-neither).
__device__ __forceinline__ void fill_one(
    const unsigned short* __restrict__ src, int R0, int kcol,
    unsigned short* slot, int s, int w, int l)
{
    const int rsub = l >> 3;
    const int csw = 8 * ((l & 7) ^ rsub);
    const int r = (s*8 + w)*8 + rsub;
    __builtin_amdgcn_global_load_lds(
        (glob_void*)(src + (size_t)(R0 + r) * HDIM + kcol + csw),
        (lds_void*)(slot + (s*8 + w)*512), 16, 0, 0);
}

// Single-buffered 256x256xBK64 MFMA loop, 64 KiB LDS -> 2 blocks/CU.
// The vmcnt(0)+barrier drain in one block overlaps the co-resident block's
// MFMA phase (m114 cross-block overlap; m97 mechanism).
__device__ __forceinline__ void run_pipeline(
    const unsigned short* __restrict__ srcA,
    const unsigned short* __restrict__ srcB,
    int rowBase, int colBase,
    unsigned short* lds, f32x4 (&acc)[8][4])
{
    const int t = threadIdx.x, w = t >> 6, l = t & 63;
    const int wr = w >> 2, wc = w & 3;
    const int lr = l & 15;
    const int sw = (l & 7) << 4;
    const int aRB = (wr*128 + lr) * 128;
    const int bRB = (wc*64  + lr) * 128;
    const int c0 = ((l >> 4) * 16) ^ sw;
    const int c1 = (64 + ((l >> 4) * 16)) ^ sw;

    unsigned short* sA = lds;
    unsigned short* sB = lds + SLOT;

    for (int kt = 0; kt < NT_K; ++kt) {
        const int kc = kt * BK;
        #pragma unroll
        for (int s = 0; s < 4; ++s) fill_one(srcA, rowBase, kc, sA, s, w, l);
        #pragma unroll
        for (int s = 0; s < 4; ++s) fill_one(srcB, colBase, kc, sB, s, w, l);
        asm volatile("s_waitcnt vmcnt(0)" ::: "memory");
        __syncthreads();

        const char* bufA = (const char*)sA;
        const char* bufB = (const char*)sB;
        #pragma unroll
        for (int kk = 0; kk < 2; ++kk) {
            const int cc = kk ? c1 : c0;
            short8 af[8], bfr[4];
            #pragma unroll
            for (int mi = 0; mi < 8; ++mi)
                af[mi] = *(const short8*)(bufA + aRB + mi*2048 + cc);
            #pragma unroll
            for (int ni = 0; ni < 4; ++ni)
                bfr[ni] = *(const short8*)(bufB + bRB + ni*2048 + cc);
            #pragma unroll
            for (int mi = 0; mi < 8; ++mi)
                #pragma unroll
                for (int ni = 0; ni < 4; ++ni)
                    acc[mi][ni] = __builtin_amdgcn_mfma_f32_16x16x32_bf16(
                        af[mi], bfr[ni], acc[mi][ni], 0, 0, 0);
        }
        __syncthreads();
    }
}

// ---- fused projection GEMM: C_mat = bf16(alpha_mat * (A @ Bt^T + bias_mat)) ----
// Bt rows [0,3*HDIM) may span 3 weight matrices; block's 256-col tile lies in one.
__global__ __launch_bounds__(NTHR, 4) void gemm_proj(
    const unsigned short* __restrict__ A,
    const unsigned short* __restrict__ Bt,
    const float* __restrict__ bias0, const float* __restrict__ bias1,
    const float* __restrict__ bias2,
    unsigned short* __restrict__ C0, unsigned short* __restrict__ C1,
    unsigned short* __restrict__ C2,
    float al0, float al1, float al2, int gx)
{
    __shared__ __align__(16) unsigned short lds[2 * SLOT];
    const int nwg = gridDim.x, bid = blockIdx.x;
    const int swz = (bid & 7) * (nwg >> 3) + (bid >> 3);
    const int bx = swz % gx, by = swz / gx;
    const int rowBase = by * BM, colBase = bx * BN;

    f32x4 acc[8][4] = {};
    run_pipeline(A, Bt, rowBase, colBase, lds, acc);

    const int t = threadIdx.x, w = t >> 6, l = t & 63;
    const int wr = w >> 2, wc = w & 3;
    const int lr = l & 15;

    const int mat = colBase >> 10;
    unsigned short* Cm = (mat == 0) ? C0 : (mat == 1 ? C1 : C2);
    const float* bm    = (mat == 0) ? bias0 : (mat == 1 ? bias1 : bias2);
    const float am     = (mat == 0) ? al0 : (mat == 1 ? al1 : al2);
    const int lcb = colBase & (HDIM - 1);

    #pragma unroll
    for (int ni = 0; ni < 4; ++ni) {
        const int col = lcb + wc*64 + ni*16 + lr;
        const float bv = bm[col];
        #pragma unroll
        for (int mi = 0; mi < 8; ++mi) {
            const int row0 = rowBase + wr*128 + mi*16 + (l >> 4) * 4;
            #pragma unroll
            for (int j = 0; j < 4; ++j)
                Cm[(size_t)(row0 + j) * HDIM + col] = f2bf(am * (acc[mi][ni][j] + bv));
        }
    }
}

// ---- per batch: A[a,b]=Q[a,:]·K[b,:]; colsum[b]+=sum_a exp(A[a,b]); diag[l]=A[l,l] ----
__global__ __launch_bounds__(NTHR, 4) void qk_colsum_diag_256(
    const unsigned short* __restrict__ Q,
    const unsigned short* __restrict__ K,
    float* __restrict__ colsum, float* __restrict__ diagv)
{
    __shared__ __align__(16) unsigned short lds[2 * SLOT];
    const int n = blockIdx.z;
    const unsigned short* Qn = Q + (size_t)n * LLEN * HDIM;
    const unsigned short* Kn = K + (size_t)n * LLEN * HDIM;
    const int rowBase = blockIdx.y * BM;
    const int colBase = blockIdx.x * BN;

    f32x4 acc[8][4] = {};
    run_pipeline(Qn, Kn, rowBase, colBase, lds, acc);

    const int t = threadIdx.x, w = t >> 6, l = t & 63;
    const int wr = w >> 2, wc = w & 3;
    const int lr = l & 15;

    // column sums of exp over this wave's 128 rows
    #pragma unroll
    for (int ni = 0; ni < 4; ++ni) {
        float s = 0.f;
        #pragma unroll
        for (int mi = 0; mi < 8; ++mi)
            #pragma unroll
            for (int j = 0; j < 4; ++j)
                s += __expf(acc[mi][ni][j]);
        s += __shfl_xor(s, 16);
        s += __shfl_xor(s, 32);
        if (l < 16)
            atomicAdd(&colsum[(size_t)n * LLEN + colBase + wc*64 + ni*16 + l], s);
    }

    // diagonal entries (pre-exp)
    if (rowBase == colBase && (wc >> 1) == wr) {
        #pragma unroll
        for (int mi = 0; mi < 8; ++mi)
            #pragma unroll
            for (int ni = 0; ni < 4; ++ni)
                #pragma unroll
                for (int j = 0; j < 4; ++j) {
                    const int rr = wr*128 + mi*16 + (l >> 4)*4 + j;
                    const int cc = wc*64 + ni*16 + lr;
                    if (rr == cc)
                        diagv[(size_t)n * LLEN + rowBase + rr] = acc[mi][ni][j];
                }
    }
}

// ---- fp32 -> bf16 cast, 8 elems/thread ----
__global__ __launch_bounds__(256) void cast_f32_bf16(
    const float* __restrict__ in, unsigned short* __restrict__ outp, int n8)
{
    int i = blockIdx.x * 256 + threadIdx.x;
    if (i >= n8) return;
    const float4* p = reinterpret_cast<const float4*>(in) + (size_t)i * 2;
    float4 a = p[0], b = p[1];
    short8 o;
    o[0] = (short)f2bf(a.x); o[1] = (short)f2bf(a.y);
    o[2] = (short)f2bf(a.z); o[3] = (short)f2bf(a.w);
    o[4] = (short)f2bf(b.x); o[5] = (short)f2bf(b.y);
    o[6] = (short)f2bf(b.z); o[7] = (short)f2bf(b.w);
    *(reinterpret_cast<short8*>(outp) + i) = o;
}

// ---- all four W (K x N fp32) -> Wt (N x K bf16), z selects the matrix ----
__global__ __launch_bounds__(256) void transpose_cast4(
    const float* __restrict__ W0, const float* __restrict__ W1,
    const float* __restrict__ W2, const float* __restrict__ W3,
    unsigned short* __restrict__ Wt)
{
    const int z = blockIdx.z;
    const float* W = (z == 0) ? W0 : (z == 1) ? W1 : (z == 2) ? W2 : W3;
    unsigned short* dst = Wt + (size_t)z * HDIM * HDIM;
    __shared__ float tile[32][33];
    const int tx = threadIdx.x & 31, ty = threadIdx.x >> 5;
    const int c0 = blockIdx.x * 32, r0 = blockIdx.y * 32;
    #pragma unroll
    for (int r = 0; r < 4; ++r)
        tile[ty + r*8][tx] = W[(size_t)(r0 + ty + r*8) * HDIM + c0 + tx];
    __syncthreads();
    #pragma unroll
    for (int r = 0; r < 4; ++r)
        dst[(size_t)(c0 + ty + r*8) * HDIM + r0 + tx] = f2bf(tile[tx][ty + r*8]);
}

// ---- h1 = bf16( LN(diag*V + X) * g1 + b1 ) ----
__global__ __launch_bounds__(256) void ln1_kernel(
    const unsigned short* __restrict__ Vb, const float* __restrict__ X,
    const float* __restrict__ colsum, const float* __restrict__ diagval,
    const float* __restrict__ g1, const float* __restrict__ b1,
    unsigned short* __restrict__ h1)
{
    const int row = blockIdx.x;
    const size_t base = (size_t)row * HDIM;
    const float dv = __expf(diagval[row]) / colsum[row];
    const int h0 = threadIdx.x * 4;

    ushort4v vv = *reinterpret_cast<const ushort4v*>(&Vb[base + h0]);
    float4 xx = *reinterpret_cast<const float4*>(&X[base + h0]);
    float y[4];
    y[0] = dv * bf2f(vv[0]) + xx.x; y[1] = dv * bf2f(vv[1]) + xx.y;
    y[2] = dv * bf2f(vv[2]) + xx.z; y[3] = dv * bf2f(vv[3]) + xx.w;

    float s = y[0]+y[1]+y[2]+y[3];
    float s2 = y[0]*y[0]+y[1]*y[1]+y[2]*y[2]+y[3]*y[3];
    #pragma unroll
    for (int off = 32; off > 0; off >>= 1) {
        s  += __shfl_down(s,  off);
        s2 += __shfl_down(s2, off);
    }
    __shared__ float ws1[4], ws2[4];
    const int wid = threadIdx.x >> 6;
    if ((threadIdx.x & 63) == 0) { ws1[wid] = s; ws2[wid] = s2; }
    __syncthreads();
    const float S  = ws1[0]+ws1[1]+ws1[2]+ws1[3];
    const float S2 = ws2[0]+ws2[1]+ws2[2]+ws2[3];
    const float m   = S  * (1.0f / HDIM);
    const float var = S2 * (1.0f / HDIM) - m*m;
    const float inv = rsqrtf(var + LNEPS);

    float4 gg = *reinterpret_cast<const float4*>(&g1[h0]);
    float4 bb = *reinterpret_cast<const float4*>(&b1[h0]);
    ushort4v o;
    o[0] = f2bf((y[0]-m)*inv*gg.x + bb.x);
    o[1] = f2bf((y[1]-m)*inv*gg.y + bb.y);
    o[2] = f2bf((y[2]-m)*inv*gg.z + bb.z);
    o[3] = f2bf((y[3]-m)*inv*gg.w + bb.w);
    *reinterpret_cast<ushort4v*>(&h1[base + h0]) = o;
}

// ---- out = fp32( LN(G + h1) * g2 + b2 ) ----
__global__ __launch_bounds__(256) void ln2_kernel(
    const unsigned short* __restrict__ Gb, const unsigned short* __restrict__ h1b,
    const float* __restrict__ g2, const float* __restrict__ b2,
    float* __restrict__ out)
{
    const int row = blockIdx.x;
    const size_t base = (size_t)row * HDIM;
    const int h0 = threadIdx.x * 4;

    ushort4v gv = *reinterpret_cast<const ushort4v*>(&Gb[base + h0]);
    ushort4v hv = *reinterpret_cast<const ushort4v*>(&h1b[base + h0]);
    float y[4];
    y[0] = bf2f(gv[0]) + bf2f(hv[0]); y[1] = bf2f(gv[1]) + bf2f(hv[1]);
    y[2] = bf2f(gv[2]) + bf2f(hv[2]); y[3] = bf2f(gv[3]) + bf2f(hv[3]);

    float s = y[0]+y[1]+y[2]+y[3];
    float s2 = y[0]*y[0]+y[1]*y[1]+y[2]*y[2]+y[3]*y[3];
    #pragma unroll
    for (int off = 32; off > 0; off >>= 1) {
        s  += __shfl_down(s,  off);
        s2 += __shfl_down(s2, off);
    }
    __shared__ float ws1[4], ws2[4];
    const int wid = threadIdx.x >> 6;
    if ((threadIdx.x & 63) == 0) { ws1[wid] = s; ws2[wid] = s2; }
    __syncthreads();
    const float S  = ws1[0]+ws1[1]+ws1[2]+ws1[3];
    const float S2 = ws2[0]+ws2[1]+ws2[2]+ws2[3];
    const float m   = S  * (1.0f / HDIM);
    const float var = S2 * (1.0f / HDIM) - m*m;
    const float inv = rsqrtf(var + LNEPS);

    float4 gg = *reinterpret_cast<const float4*>(&g2[h0]);
    float4 bb = *reinterpret_cast<const float4*>(&b2[h0]);
    float4 o;
    o.x = (y[0]-m)*inv*gg.x + bb.x;
    o.y = (y[1]-m)*inv*gg.y + bb.y;
    o.z = (y[2]-m)*inv*gg.z + bb.z;
    o.w = (y[3]-m)*inv*gg.w + bb.w;
    *reinterpret_cast<float4*>(&out[base + h0]) = o;
}

extern "C" void kernel_launch(void* const* d_in, const int* in_sizes, int n_in,
                              void* d_out, int out_size, void* d_ws, size_t ws_size,
                              hipStream_t stream) {
    (void)in_sizes; (void)n_in; (void)out_size; (void)ws_size;
    const float* X  = (const float*)d_in[0];
    const float* Wq = (const float*)d_in[1];
    const float* bq = (const float*)d_in[2];
    const float* Wk = (const float*)d_in[3];
    const float* bk = (const float*)d_in[4];
    const float* Wv = (const float*)d_in[5];
    const float* bv = (const float*)d_in[6];
    const float* Wf = (const float*)d_in[7];
    const float* bf = (const float*)d_in[8];
    const float* g1 = (const float*)d_in[9];
    const float* b1 = (const float*)d_in[10];
    const float* g2 = (const float*)d_in[11];
    const float* b2 = (const float*)d_in[12];
    float* out = (float*)d_out;

    const size_t MATE = (size_t)NB * LLEN * HDIM;   // 16,777,216 elements
    const size_t WE   = (size_t)HDIM * HDIM;

    // d_out (64 MiB) doubles as staging: Xb bf16 [0,32MiB), Vb bf16 [32,64MiB).
    unsigned short* Xb  = (unsigned short*)d_out;
    unsigned short* Vb  = Xb + MATE;

    unsigned short* Qb  = (unsigned short*)d_ws;    // 32 MiB
    unsigned short* Kb  = Qb + MATE;                // 32 MiB
    unsigned short* WqT = Kb + MATE;                // contiguous 3*WE: [WqT|WkT|WvT]
    unsigned short* WkT = WqT + WE;
    unsigned short* WvT = WkT + WE;
    unsigned short* WfT = WvT + WE;
    float* colsum = (float*)(WfT + WE);             // 64 KiB
    float* diagv  = colsum + (size_t)NB * LLEN;     // 64 KiB
    unsigned short* h1b = Qb;                       // reuse after qk
    unsigned short* Gb  = Kb;                       // reuse after qk

    const int M = NB * LLEN;            // 16384
    const float scale = 1.0f / 32.0f;   // 1/sqrt(H)

    hipMemsetAsync(colsum, 0, (size_t)NB * LLEN * sizeof(float), stream);

    const int n8 = (int)(MATE / 8);
    cast_f32_bf16<<<n8 / 256, 256, 0, stream>>>(X, Xb, n8);

    // all four weight transposes in one launch; dst = WqT base (WfT = z==3 slot)
    {
        dim3 tgrid(HDIM / 32, HDIM / 32, 4);
        transpose_cast4<<<tgrid, 256, 0, stream>>>(Wq, Wk, Wv, Wf, WqT);
    }

    // fused QKV projection: B rows 0-3071 = [WqT|WkT|WvT]
    {
        const int gx = 3 * HDIM / BN;       // 12
        const int nwg = gx * (M / BM);      // 768 (%8==0, swizzle bijective)
        gemm_proj<<<nwg, NTHR, 0, stream>>>(Xb, WqT, bq, bk, bv,
                                            Qb, Kb, Vb, scale, scale, 1.0f, gx);
    }

    dim3 qgrid(LLEN / BN, LLEN / BM, NB);   // (8, 8, 8)
    qk_colsum_diag_256<<<qgrid, NTHR, 0, stream>>>(Qb, Kb, colsum, diagv);

    ln1_kernel<<<M, 256, 0, stream>>>(Vb, X, colsum, diagv, g1, b1, h1b);

    // FF GEMM: single-matrix path (mat always 0)
    {
        const int gx = HDIM / BN;           // 4
        const int nwg = gx * (M / BM);      // 256
        gemm_proj<<<nwg, NTHR, 0, stream>>>(h1b, WfT, bf, bf, bf,
                                            Gb, Gb, Gb, 1.0f, 1.0f, 1.0f, gx);
    }

    ln2_kernel<<<M, 256, 0, stream>>>(Gb, h1b, g2, b2, out);
}

// Round 7
// 286.590 us; speedup vs baseline: 4.3424x; 4.3424x over previous
//
#include <hip/hip_runtime.h>
#include <math.h>

#define NB   8
#define LLEN 2048
#define HDIM 1024
#define LNEPS 1e-5f

#define BM 256
#define BN 256
#define BK 64
#define NT_K (HDIM / BK)   // 16 K-tiles
#define NTHR 512
#define SLOT (BM * BK)     // 16384 shorts = 32 KiB per operand slot

typedef __attribute__((ext_vector_type(8))) short short8;
typedef __attribute__((ext_vector_type(4))) unsigned short ushort4v;
typedef __attribute__((ext_vector_type(4))) float f32x4;

typedef __attribute__((address_space(3))) void lds_void;
typedef const __attribute__((address_space(1))) void glob_void;

__device__ __forceinline__ unsigned short f2bf(float f) {
    union { float f; unsigned u; } v; v.f = f;
    unsigned r = v.u + 0x7FFFu + ((v.u >> 16) & 1u);
    return (unsigned short)(r >> 16);
}
__device__ __forceinline__ float bf2f(unsigned short h) {
    union { unsigned u; float f; } v; v.u = ((unsigned)h) << 16;
    return v.f;
}

__device__ __forceinline__ void wg_barrier() {
    asm volatile("" ::: "memory");
    __builtin_amdgcn_s_barrier();
    asm volatile("" ::: "memory");
}

// Stage one 256x64 bf16 tile into LDS with XOR-swizzled layout
// byte(r,cb) = r*128 + (cb ^ ((r&7)<<4)); swizzle pre-applied to the
// per-lane GLOBAL source (rule 21), LDS dest stays linear.
__device__ __forceinline__ void stage_tile(
    const unsigned short* __restrict__ src, int R0, int kcol0,
    unsigned short* ldsDst, int w, int lane)
{
    const int rsub = lane >> 3;
    const int csw  = 8 * ((lane & 7) ^ rsub);
    #pragma unroll
    for (int s = 0; s < 4; ++s) {
        const int r = (s*8 + w)*8 + rsub;
        const unsigned short* g = src + (size_t)(R0 + r) * HDIM + kcol0 + csw;
        __builtin_amdgcn_global_load_lds(
            (glob_void*)g, (lds_void*)(ldsDst + (s*8 + w)*512), 16, 0, 0);
    }
}

// Round-3 proven pipeline: 256x256xBK64, depth-2 prefetch, counted vmcnt(8),
// 2 barriers per K-tile, 128 KiB LDS (1 block/CU), VGPR free to ~200.
__device__ __forceinline__ void run_pipeline(
    const unsigned short* __restrict__ srcA,
    const unsigned short* __restrict__ srcB,
    int rowBase, int colBase,
    unsigned short* lds, f32x4 (&acc)[8][4])
{
    const int t = threadIdx.x, w = t >> 6, l = t & 63;
    const int wr = w >> 2, wc = w & 3;
    const int lr = l & 15;
    const int sw = (l & 7) << 4;
    const int aRB = (wr*128 + lr) * 128;
    const int bRB = (wc*64  + lr) * 128;
    const int c0 = ((l >> 4) * 16) ^ sw;
    const int c1 = (64 + ((l >> 4) * 16)) ^ sw;

    unsigned short* sA[2] = { lds,            lds + 2*SLOT };
    unsigned short* sB[2] = { lds + SLOT,     lds + 3*SLOT };

    stage_tile(srcA, rowBase, 0,  sA[0], w, l);
    stage_tile(srcB, colBase, 0,  sB[0], w, l);
    stage_tile(srcA, rowBase, BK, sA[1], w, l);
    stage_tile(srcB, colBase, BK, sB[1], w, l);
    asm volatile("s_waitcnt vmcnt(8)" ::: "memory");
    wg_barrier();

    for (int kt = 0; kt < NT_K; ++kt) {
        const char* bufA = (const char*)sA[kt & 1];
        const char* bufB = (const char*)sB[kt & 1];
        #pragma unroll
        for (int kk = 0; kk < 2; ++kk) {
            const int cc = kk ? c1 : c0;
            short8 af[8], bfr[4];
            #pragma unroll
            for (int mi = 0; mi < 8; ++mi)
                af[mi] = *(const short8*)(bufA + aRB + mi*2048 + cc);
            #pragma unroll
            for (int ni = 0; ni < 4; ++ni)
                bfr[ni] = *(const short8*)(bufB + bRB + ni*2048 + cc);
            #pragma unroll
            for (int mi = 0; mi < 8; ++mi)
                #pragma unroll
                for (int ni = 0; ni < 4; ++ni)
                    acc[mi][ni] = __builtin_amdgcn_mfma_f32_16x16x32_bf16(
                        af[mi], bfr[ni], acc[mi][ni], 0, 0, 0);
        }
        if (kt == NT_K - 1) break;
        wg_barrier();
        if (kt + 2 < NT_K) {
            stage_tile(srcA, rowBase, (kt+2)*BK, sA[kt&1], w, l);
            stage_tile(srcB, colBase, (kt+2)*BK, sB[kt&1], w, l);
            asm volatile("s_waitcnt vmcnt(8)" ::: "memory");
        } else {
            asm volatile("s_waitcnt vmcnt(0)" ::: "memory");
        }
        wg_barrier();
    }
}

// ---- multi-output GEMM: C_mat = bf16(alpha_mat * (A @ Bt^T + bias_mat)) ----
__global__ __launch_bounds__(NTHR, 2) void gemm_proj(
    const unsigned short* __restrict__ A,
    const unsigned short* __restrict__ Bt,
    const float* __restrict__ bias0, const float* __restrict__ bias1,
    const float* __restrict__ bias2,
    unsigned short* __restrict__ C0, unsigned short* __restrict__ C1,
    unsigned short* __restrict__ C2,
    float al0, float al1, float al2, int gx)
{
    __shared__ __align__(16) unsigned short lds[4 * SLOT];
    const int nwg = gridDim.x, bid = blockIdx.x;
    const int swz = (bid & 7) * (nwg >> 3) + (bid >> 3);
    const int bx = swz % gx, by = swz / gx;
    const int rowBase = by * BM, colBase = bx * BN;

    f32x4 acc[8][4] = {};
    run_pipeline(A, Bt, rowBase, colBase, lds, acc);

    const int t = threadIdx.x, w = t >> 6, l = t & 63;
    const int wr = w >> 2, wc = w & 3;
    const int lr = l & 15;

    const int mat = colBase >> 10;
    unsigned short* Cm = (mat == 0) ? C0 : (mat == 1 ? C1 : C2);
    const float* bm    = (mat == 0) ? bias0 : (mat == 1 ? bias1 : bias2);
    const float am     = (mat == 0) ? al0 : (mat == 1 ? al1 : al2);
    const int lcb = colBase & (HDIM - 1);

    #pragma unroll
    for (int ni = 0; ni < 4; ++ni) {
        const int col = lcb + wc*64 + ni*16 + lr;
        const float bv = bm[col];
        #pragma unroll
        for (int mi = 0; mi < 8; ++mi) {
            const int row0 = rowBase + wr*128 + mi*16 + (l >> 4) * 4;
            #pragma unroll
            for (int j = 0; j < 4; ++j)
                Cm[(size_t)(row0 + j) * HDIM + col] = f2bf(am * (acc[mi][ni][j] + bv));
        }
    }
}

// ---- per batch: S[a,b]=Xq0[a,:]·Xb[b,:]; colsum[b]+=sum_a exp(S+u[a]); diag=S[l,l] ----
__global__ __launch_bounds__(NTHR, 2) void qk_colsum_diag_256(
    const unsigned short* __restrict__ Xq0,
    const unsigned short* __restrict__ Xb,
    const float* __restrict__ uvec,
    float* __restrict__ colsum, float* __restrict__ diagv)
{
    __shared__ __align__(16) unsigned short lds[4 * SLOT];
    const int n = blockIdx.z;
    const unsigned short* An = Xq0 + (size_t)n * LLEN * HDIM;
    const unsigned short* Bn = Xb  + (size_t)n * LLEN * HDIM;
    const int rowBase = blockIdx.y * BM;
    const int colBase = blockIdx.x * BN;

    f32x4 acc[8][4] = {};
    run_pipeline(An, Bn, rowBase, colBase, lds, acc);

    const int t = threadIdx.x, w = t >> 6, l = t & 63;
    const int wr = w >> 2, wc = w & 3;
    const int lr = l & 15;

    // per-row bias term u'[a] (cached once, reused across ni)
    float ur[8][4];
    #pragma unroll
    for (int mi = 0; mi < 8; ++mi)
        #pragma unroll
        for (int j = 0; j < 4; ++j)
            ur[mi][j] = uvec[(size_t)n * LLEN + rowBase + wr*128 + mi*16 + (l>>4)*4 + j];

    #pragma unroll
    for (int ni = 0; ni < 4; ++ni) {
        float s = 0.f;
        #pragma unroll
        for (int mi = 0; mi < 8; ++mi)
            #pragma unroll
            for (int j = 0; j < 4; ++j)
                s += __expf(acc[mi][ni][j] + ur[mi][j]);
        s += __shfl_xor(s, 16);
        s += __shfl_xor(s, 32);
        if (l < 16)
            atomicAdd(&colsum[(size_t)n * LLEN + colBase + wc*64 + ni*16 + l], s);
    }

    if (rowBase == colBase && (wc >> 1) == wr) {
        #pragma unroll
        for (int mi = 0; mi < 8; ++mi)
            #pragma unroll
            for (int ni = 0; ni < 4; ++ni)
                #pragma unroll
                for (int j = 0; j < 4; ++j) {
                    const int rr = wr*128 + mi*16 + (l >> 4)*4 + j;
                    const int cc = wc*64 + ni*16 + lr;
                    if (rr == cc)
                        diagv[(size_t)n * LLEN + rowBase + rr] = acc[mi][ni][j];
                }
    }
}

// ---- fp32 -> bf16 cast, 8 elems/thread ----
__global__ __launch_bounds__(256) void cast_f32_bf16(
    const float* __restrict__ in, unsigned short* __restrict__ outp, int n8)
{
    int i = blockIdx.x * 256 + threadIdx.x;
    if (i >= n8) return;
    const float4* p = reinterpret_cast<const float4*>(in) + (size_t)i * 2;
    float4 a = p[0], b = p[1];
    short8 o;
    o[0] = (short)f2bf(a.x); o[1] = (short)f2bf(a.y);
    o[2] = (short)f2bf(a.z); o[3] = (short)f2bf(a.w);
    o[4] = (short)f2bf(b.x); o[5] = (short)f2bf(b.y);
    o[6] = (short)f2bf(b.z); o[7] = (short)f2bf(b.w);
    *(reinterpret_cast<short8*>(outp) + i) = o;
}

// ---- Wv, Wf (K x N fp32) -> Wt (N x K bf16), z selects ----
__global__ __launch_bounds__(256) void transpose_cast2(
    const float* __restrict__ W0, const float* __restrict__ W1,
    unsigned short* __restrict__ Wt)
{
    const int z = blockIdx.z;
    const float* W = (z == 0) ? W0 : W1;
    unsigned short* dst = Wt + (size_t)z * HDIM * HDIM;
    __shared__ float tile[32][33];
    const int tx = threadIdx.x & 31, ty = threadIdx.x >> 5;
    const int c0 = blockIdx.x * 32, r0 = blockIdx.y * 32;
    #pragma unroll
    for (int r = 0; r < 4; ++r)
        tile[ty + r*8][tx] = W[(size_t)(r0 + ty + r*8) * HDIM + c0 + tx];
    __syncthreads();
    #pragma unroll
    for (int r = 0; r < 4; ++r)
        dst[(size_t)(c0 + ty + r*8) * HDIM + r0 + tx] = f2bf(tile[tx][ty + r*8]);
}

// ---- p[i] = Wq[i,:] . bk ; one wave per row ----
__global__ __launch_bounds__(256) void pvec_kernel(
    const float* __restrict__ Wq, const float* __restrict__ bk,
    float* __restrict__ p)
{
    const int row = blockIdx.x * 4 + (threadIdx.x >> 6);
    const int l = threadIdx.x & 63;
    float s = 0.f;
    #pragma unroll
    for (int c = 0; c < HDIM; c += 64)
        s += Wq[(size_t)row * HDIM + c + l] * bk[c + l];
    #pragma unroll
    for (int off = 32; off > 0; off >>= 1) s += __shfl_down(s, off);
    if (l == 0) p[row] = s;
}

// ---- u[a] = sc2 * Xb[a,:] . p ; one wave per row ----
__global__ __launch_bounds__(256) void uvec_kernel(
    const unsigned short* __restrict__ Xb, const float* __restrict__ p,
    float* __restrict__ u, float sc2)
{
    const int row = blockIdx.x * 4 + (threadIdx.x >> 6);
    const int l = threadIdx.x & 63;
    const unsigned short* xr = Xb + (size_t)row * HDIM + l * 16;
    float s = 0.f;
    #pragma unroll
    for (int k = 0; k < 2; ++k) {
        short8 v = *reinterpret_cast<const short8*>(xr + k*8);
        #pragma unroll
        for (int j = 0; j < 8; ++j)
            s += bf2f((unsigned short)v[j]) * p[l*16 + k*8 + j];
    }
    #pragma unroll
    for (int off = 32; off > 0; off >>= 1) s += __shfl_down(s, off);
    if (l == 0) u[row] = s * sc2;
}

// ---- h1 = bf16( LN(diag*V + X) * g1 + b1 ), diag = exp(S_ll+u_l)/colsum ----
__global__ __launch_bounds__(256) void ln1_kernel(
    const unsigned short* __restrict__ Vb, const float* __restrict__ X,
    const float* __restrict__ colsum, const float* __restrict__ diagval,
    const float* __restrict__ uvec,
    const float* __restrict__ g1, const float* __restrict__ b1,
    unsigned short* __restrict__ h1)
{
    const int row = blockIdx.x;
    const size_t base = (size_t)row * HDIM;
    const float dv = __expf(diagval[row] + uvec[row]) / colsum[row];
    const int h0 = threadIdx.x * 4;

    ushort4v vv = *reinterpret_cast<const ushort4v*>(&Vb[base + h0]);
    float4 xx = *reinterpret_cast<const float4*>(&X[base + h0]);
    float y[4];
    y[0] = dv * bf2f(vv[0]) + xx.x; y[1] = dv * bf2f(vv[1]) + xx.y;
    y[2] = dv * bf2f(vv[2]) + xx.z; y[3] = dv * bf2f(vv[3]) + xx.w;

    float s = y[0]+y[1]+y[2]+y[3];
    float s2 = y[0]*y[0]+y[1]*y[1]+y[2]*y[2]+y[3]*y[3];
    #pragma unroll
    for (int off = 32; off > 0; off >>= 1) {
        s  += __shfl_down(s,  off);
        s2 += __shfl_down(s2, off);
    }
    __shared__ float ws1[4], ws2[4];
    const int wid = threadIdx.x >> 6;
    if ((threadIdx.x & 63) == 0) { ws1[wid] = s; ws2[wid] = s2; }
    __syncthreads();
    const float S  = ws1[0]+ws1[1]+ws1[2]+ws1[3];
    const float S2 = ws2[0]+ws2[1]+ws2[2]+ws2[3];
    const float m   = S  * (1.0f / HDIM);
    const float var = S2 * (1.0f / HDIM) - m*m;
    const float inv = rsqrtf(var + LNEPS);

    float4 gg = *reinterpret_cast<const float4*>(&g1[h0]);
    float4 bb = *reinterpret_cast<const float4*>(&b1[h0]);
    ushort4v o;
    o[0] = f2bf((y[0]-m)*inv*gg.x + bb.x);
    o[1] = f2bf((y[1]-m)*inv*gg.y + bb.y);
    o[2] = f2bf((y[2]-m)*inv*gg.z + bb.z);
    o[3] = f2bf((y[3]-m)*inv*gg.w + bb.w);
    *reinterpret_cast<ushort4v*>(&h1[base + h0]) = o;
}

// ---- out = fp32( LN(G + h1) * g2 + b2 ) ----
__global__ __launch_bounds__(256) void ln2_kernel(
    const unsigned short* __restrict__ Gb, const unsigned short* __restrict__ h1b,
    const float* __restrict__ g2, const float* __restrict__ b2,
    float* __restrict__ out)
{
    const int row = blockIdx.x;
    const size_t base = (size_t)row * HDIM;
    const int h0 = threadIdx.x * 4;

    ushort4v gv = *reinterpret_cast<const ushort4v*>(&Gb[base + h0]);
    ushort4v hv = *reinterpret_cast<const ushort4v*>(&h1b[base + h0]);
    float y[4];
    y[0] = bf2f(gv[0]) + bf2f(hv[0]); y[1] = bf2f(gv[1]) + bf2f(hv[1]);
    y[2] = bf2f(gv[2]) + bf2f(hv[2]); y[3] = bf2f(gv[3]) + bf2f(hv[3]);

    float s = y[0]+y[1]+y[2]+y[3];
    float s2 = y[0]*y[0]+y[1]*y[1]+y[2]*y[2]+y[3]*y[3];
    #pragma unroll
    for (int off = 32; off > 0; off >>= 1) {
        s  += __shfl_down(s,  off);
        s2 += __shfl_down(s2, off);
    }
    __shared__ float ws1[4], ws2[4];
    const int wid = threadIdx.x >> 6;
    if ((threadIdx.x & 63) == 0) { ws1[wid] = s; ws2[wid] = s2; }
    __syncthreads();
    const float S  = ws1[0]+ws1[1]+ws1[2]+ws1[3];
    const float S2 = ws2[0]+ws2[1]+ws2[2]+ws2[3];
    const float m   = S  * (1.0f / HDIM);
    const float var = S2 * (1.0f / HDIM) - m*m;
    const float inv = rsqrtf(var + LNEPS);

    float4 gg = *reinterpret_cast<const float4*>(&g2[h0]);
    float4 bb = *reinterpret_cast<const float4*>(&b2[h0]);
    float4 o;
    o.x = (y[0]-m)*inv*gg.x + bb.x;
    o.y = (y[1]-m)*inv*gg.y + bb.y;
    o.z = (y[2]-m)*inv*gg.z + bb.z;
    o.w = (y[3]-m)*inv*gg.w + bb.w;
    *reinterpret_cast<float4*>(&out[base + h0]) = o;
}

extern "C" void kernel_launch(void* const* d_in, const int* in_sizes, int n_in,
                              void* d_out, int out_size, void* d_ws, size_t ws_size,
                              hipStream_t stream) {
    (void)in_sizes; (void)n_in; (void)out_size; (void)ws_size;
    const float* X  = (const float*)d_in[0];
    const float* Wq = (const float*)d_in[1];
    const float* bq = (const float*)d_in[2];   (void)bq; // cancels in diag/colsum ratio
    const float* Wk = (const float*)d_in[3];
    const float* bk = (const float*)d_in[4];
    const float* Wv = (const float*)d_in[5];
    const float* bv = (const float*)d_in[6];
    const float* Wf = (const float*)d_in[7];
    const float* bf = (const float*)d_in[8];
    const float* g1 = (const float*)d_in[9];
    const float* b1 = (const float*)d_in[10];
    const float* g2 = (const float*)d_in[11];
    const float* b2 = (const float*)d_in[12];
    float* out = (float*)d_out;

    const size_t MATE = (size_t)NB * LLEN * HDIM;   // 16,777,216 elements
    const size_t WE   = (size_t)HDIM * HDIM;

    // d_out doubles as staging: Xb bf16 [0,32MiB), Vb bf16 [32,64MiB).
    unsigned short* Xb  = (unsigned short*)d_out;
    unsigned short* Vb  = Xb + MATE;

    unsigned short* Xq0  = (unsigned short*)d_ws;   // 32 MiB (reused as h1b)
    unsigned short* Gb   = Xq0 + MATE;              // 32 MiB
    unsigned short* WqkT = Gb + MATE;               // [WqkT|WvT] contiguous for fused proj
    unsigned short* WvT  = WqkT + WE;
    unsigned short* WfT  = WvT + WE;
    unsigned short* Wqb  = WfT + WE;
    unsigned short* Wkb  = Wqb + WE;
    float* colsum = (float*)(Wkb + WE);             // 64 KiB
    float* diagv  = colsum + (size_t)NB * LLEN;     // 64 KiB
    float* pv     = diagv + (size_t)NB * LLEN;      // 4 KiB
    float* uv     = pv + HDIM;                      // 64 KiB
    float* zvec   = uv + (size_t)NB * LLEN;         // 4 KiB (zero bias)
    unsigned short* h1b = Xq0;                      // reuse after qk

    const int M = NB * LLEN;            // 16384
    const float sc2 = 1.0f / 1024.0f;   // (1/sqrt(H))^2

    hipMemsetAsync(colsum, 0, (size_t)NB * LLEN * sizeof(float), stream);
    hipMemsetAsync(zvec, 0, HDIM * sizeof(float), stream);

    cast_f32_bf16<<<(int)(MATE/8) / 256, 256, 0, stream>>>(X, Xb, (int)(MATE/8));
    cast_f32_bf16<<<(int)(WE/8) / 256, 256, 0, stream>>>(Wq, Wqb, (int)(WE/8));
    cast_f32_bf16<<<(int)(WE/8) / 256, 256, 0, stream>>>(Wk, Wkb, (int)(WE/8));

    {
        dim3 tgrid(HDIM / 32, HDIM / 32, 2);
        transpose_cast2<<<tgrid, 256, 0, stream>>>(Wv, Wf, WvT);
    }

    // WqkT[j,i] = sc2 * sum_h Wk[j,h]*Wq[i,h]  (rows j, K-contig along i)
    gemm_proj<<<16, NTHR, 0, stream>>>(Wkb, Wqb, zvec, zvec, zvec,
                                       WqkT, WqkT, WqkT, sc2, sc2, sc2, 4);

    // u'[a] = sc2 * X[a,:] . (Wq @ bk)   (bias rank-1 term; v'/const cancel)
    pvec_kernel<<<HDIM / 4, 256, 0, stream>>>(Wq, bk, pv);
    uvec_kernel<<<M / 4, 256, 0, stream>>>(Xb, pv, uv, sc2);

    // fused [Xq0 | V] = Xb @ [WqkT | WvT]^T  (N = 2048)
    {
        const int gx = 2 * HDIM / BN;       // 8
        const int nwg = gx * (M / BM);      // 512 (%8==0)
        gemm_proj<<<nwg, NTHR, 0, stream>>>(Xb, WqkT, zvec, bv, zvec,
                                            Xq0, Vb, Vb, 1.0f, 1.0f, 1.0f, gx);
    }

    dim3 qgrid(LLEN / BN, LLEN / BM, NB);   // (8, 8, 8)
    qk_colsum_diag_256<<<qgrid, NTHR, 0, stream>>>(Xq0, Xb, uv, colsum, diagv);

    ln1_kernel<<<M, 256, 0, stream>>>(Vb, X, colsum, diagv, uv, g1, b1, h1b);

    // FF GEMM (single-matrix path)
    {
        const int gx = HDIM / BN;           // 4
        const int nwg = gx * (M / BM);      // 256
        gemm_proj<<<nwg, NTHR, 0, stream>>>(h1b, WfT, bf, bf, bf,
                                            Gb, Gb, Gb, 1.0f, 1.0f, 1.0f, gx);
    }

    ln2_kernel<<<M, 256, 0, stream>>>(Gb, h1b, g2, b2, out);
}